// Round 7
// baseline (572.097 us; speedup 1.0000x reference)
//
#include <hip/hip_runtime.h>
#include <hip/hip_bf16.h>
#include <math.h>

#define N_IMAGE 128
#define N_REG   36
#define DIM     1024
#define MAX_WORD 60
#define OT_ITERS 20
#define MARGIN_F 0.2f
#define ALPHA_F  0.1f
#define EPS_F    1e-12f

typedef short bf16x8 __attribute__((ext_vector_type(8)));
typedef float f32x4  __attribute__((ext_vector_type(4)));

// ---------------- helpers ----------------

__device__ __forceinline__ unsigned int pkbf2(float a, float b) {
    union { __hip_bfloat162 h2; unsigned int u; } cv;
    cv.h2 = __float22bfloat162_rn(make_float2(a, b));
    return cv.u;
}
__device__ __forceinline__ float lo16(unsigned int u) { return __int_as_float((int)(u << 16)); }
__device__ __forceinline__ float hi16(unsigned int u) { return __int_as_float((int)(u & 0xFFFF0000u)); }

#define SWZ(x, pat) __int_as_float(__builtin_amdgcn_ds_swizzle(__float_as_int(x), (pat)))
#define BPERM(a, x) __int_as_float(__builtin_amdgcn_ds_bpermute((a), __float_as_int(x)))
// DPP add: x += dpp_perm(x). VALU pipe only, low latency.
#define DPPADD(x, ctrl) \
    ((x) + __int_as_float(__builtin_amdgcn_update_dpp(0, __float_as_int(x), (ctrl), 0xf, 0xf, true)))

// 16-lane group sum (all 16 lanes get the sum). Pure DPP/VALU.
__device__ __forceinline__ float bfly16_sum(float x) {
    x = DPPADD(x, 0xB1);    // quad_perm ^1
    x = DPPADD(x, 0x4E);    // quad_perm ^2
    x = DPPADD(x, 0x124);   // row_ror:4
    x = DPPADD(x, 0x128);   // row_ror:8
    return x;
}
// full 64-lane sum (all lanes)
__device__ __forceinline__ float bfly64_sum(float x, int xaddr) {
    x = bfly16_sum(x);
    x += SWZ(x, 0x401F);   // ^16
    x += BPERM(xaddr, x);  // ^32
    return x;
}

// ---------------- norms (+ zero d_out for loss atomics) ----------------

__global__ void norms_kernel(const float* __restrict__ im, const float* __restrict__ s,
                             float* __restrict__ inv_im, float* __restrict__ inv_cap,
                             float* __restrict__ out) {
    if (blockIdx.x == 0 && threadIdx.x == 0) { out[0] = 0.0f; out[1] = 0.0f; }
    const int NIM = N_IMAGE * N_REG;     // 4608
    const int NS  = N_IMAGE * MAX_WORD;  // 7680
    int row  = blockIdx.x * 4 + (threadIdx.x >> 6);
    int lane = threadIdx.x & 63;
    if (row >= NIM + NS) return;
    const float* base = (row < NIM) ? (im + (size_t)row * DIM)
                                    : (s  + (size_t)(row - NIM) * DIM);
    const float4* b4 = (const float4*)base;
    float acc = 0.0f;
    for (int k = lane; k < DIM / 4; k += 64) {
        float4 v = b4[k];
        acc += v.x * v.x + v.y * v.y + v.z * v.z + v.w * v.w;
    }
    for (int off = 32; off; off >>= 1) acc += __shfl_down(acc, off, 64);
    if (lane == 0) {
        float inv = 1.0f / (sqrtf(acc) + EPS_F);
        if (row < NIM) inv_im[row] = inv;
        else           inv_cap[row - NIM] = inv;
    }
}

// ---------------- fused pair kernel ----------------
// Block = (caption i, image group of 4). Wave v owns pair (i, b0+v).
// GEMM: A-fragments direct from global per lane; B staged in LDS double buffer.
// D in MFMA C-layout: acc[rt*4+ct][p] = M[r][w], r = rt*16+q*4+p, w = ct*16+l15.
// OT: register-resident in C-layout. A and T both bf16-packed (24+24 dwords);
// acc's live range is closed BEFORE t-init so the OT loop state (~75 regs)
// fits in architected VGPRs at launch_bounds(256,4) -> no AGPR round-trips.

__global__ __launch_bounds__(256, 4)
void pair_kernel(const float* __restrict__ im, const float* __restrict__ s,
                 const int* __restrict__ s_l,
                 const float* __restrict__ inv_im, const float* __restrict__ inv_cap,
                 float* __restrict__ S, float* __restrict__ SOT) {
    const int cap  = blockIdx.x;         // caption index i
    const int b0   = blockIdx.y * 4;     // first image of this block
    const int tid  = threadIdx.x;
    const int lane = tid & 63;
    const int wv   = tid >> 6;           // wave id = local image
    const int q    = lane >> 4;          // 16-lane group within wave
    const int l15  = lane & 15;
    const int q4   = tid & 15;           // staging column slot (16B granules)
    const int row0 = tid >> 4;           // staging row base (0..15)
    const int xaddr = ((lane ^ 32) << 2);

    // LDS: B double buffer 2 x (64 rows x 144B) = 18432B
    __shared__ __align__(16) char smem[18432];
    __shared__ float invImS[144];
    __shared__ float invCapS[60];

    if (tid < 144) invImS[tid] = inv_im[b0 * 36 + tid];
    else if (tid < 204) invCapS[tid - 144] = inv_cap[cap * 60 + (tid - 144)];

    const int   m     = s_l[cap];        // n_word, 10..60
    const float mf    = (float)m;
    const float inv_m = 1.0f / mf;

    // zero B pad rows (60..63) of both buffers once (never written again)
    if (tid < 72) {
        const int bufi = (tid >= 36);
        *(float4*)(smem + bufi * 9216 + 60 * 144 + (tid - bufi * 36) * 16) =
            make_float4(0.f, 0.f, 0.f, 0.f);
    }

    // per-lane column info (4 columns: w = ct*16 + l15)
    float icap[4]; bool vw[4];
    #pragma unroll
    for (int ct = 0; ct < 4; ++ct) {
        const int w = ct * 16 + l15;
        vw[ct]   = (w < m);
        icap[ct] = (w < 60) ? 0.0f : 0.0f;   // filled after barrier below
    }

    unsigned int apk[12][2];     // A = exp(-2C), bf16-packed
    float mxv[4] = {-3e38f, -3e38f, -3e38f, -3e38f};

    {   // ---- acc live range: GEMM + A-matrix extraction only ----
        f32x4 acc[12];
        #pragma unroll
        for (int t = 0; t < 12; ++t) acc[t] = (f32x4){0.f, 0.f, 0.f, 0.f};

        const float* baseA = im + ((size_t)(b0 + wv) * 36) * 1024;  // this wave's image
        const float* baseB = s  + ((size_t)cap * 60) * 1024 + q4 * 4;

        for (int c = 0; c < 16; ++c) {
            char* sBuf = smem + (c & 1) * 9216;

            // A prefetch + pack: 6 fragments (2 K-halves x 3 row-tiles), no LDS.
            union { bf16x8 v; unsigned int u[4]; } afr[6];
            #pragma unroll
            for (int h = 0; h < 2; ++h) {
                #pragma unroll
                for (int rt = 0; rt < 3; ++rt) {
                    const bool okA = (rt < 2) || (l15 < 4);          // row < 36
                    const int  rowc = rt * 16 + (okA ? l15 : 0);     // clamped (safe addr)
                    const float* p = baseA + (size_t)rowc * 1024 + c * 64 + h * 32 + q * 8;
                    float4 v0 = *(const float4*)p;
                    float4 v1 = *(const float4*)(p + 4);
                    const int j6 = h * 3 + rt;
                    afr[j6].u[0] = okA ? pkbf2(v0.x, v0.y) : 0u;
                    afr[j6].u[1] = okA ? pkbf2(v0.z, v0.w) : 0u;
                    afr[j6].u[2] = okA ? pkbf2(v1.x, v1.y) : 0u;
                    afr[j6].u[3] = okA ? pkbf2(v1.z, v1.w) : 0u;
                }
            }

            // B stage: 4 row-slots per thread into buffer c&1
            const float* pB = baseB + c * 64;
            #pragma unroll
            for (int j = 0; j < 4; ++j) {
                const int r = row0 + 16 * j;                         // < 64
                if (j < 3 || row0 < 12) {                            // valid iff r < 60
                    float4 v = *(const float4*)(pB + (size_t)r * 1024);
                    uint2 w2; w2.x = pkbf2(v.x, v.y); w2.y = pkbf2(v.z, v.w);
                    *(uint2*)(sBuf + r * 144 + q4 * 8) = w2;
                }
            }
            __syncthreads();

            #pragma unroll
            for (int h = 0; h < 2; ++h) {
                bf16x8 bfr[4];
                #pragma unroll
                for (int ct = 0; ct < 4; ++ct)
                    bfr[ct] = *(const bf16x8*)(sBuf + (ct * 16 + l15) * 144 + h * 64 + q * 16);
                #pragma unroll
                for (int rt = 0; rt < 3; ++rt) {
                    #pragma unroll
                    for (int ct = 0; ct < 4; ++ct)
                        acc[rt * 4 + ct] = __builtin_amdgcn_mfma_f32_16x16x32_bf16(
                            afr[h * 3 + rt].v, bfr[ct], acc[rt * 4 + ct], 0, 0, 0);
                }
            }
            __syncthreads();   // protects buffer reuse at chunk c+2
        }

        // fill icap now (barriers above ordered the LDS writes)
        #pragma unroll
        for (int ct = 0; ct < 4; ++ct) {
            const int w = ct * 16 + l15;
            icap[ct] = (w < 60) ? invCapS[w] : 0.0f;
        }

        // ---- extract A = exp(-2C) + column maxes; acc dies here ----
        #pragma unroll
        for (int j = 0; j < 12; ++j) {
            const int rt = j >> 2, p = j & 3;
            const int r  = rt * 16 + q * 4 + p;                  // < 48
            const bool rowok = (rt < 2) || (q == 0);             // r < 36
            const float iir = rowok ? invImS[wv * 36 + (r < 36 ? r : 0)] : 0.0f;
            float av[4];
            #pragma unroll
            for (int ct = 0; ct < 4; ++ct) {
                const float Mv = acc[rt * 4 + ct][p];
                mxv[ct] = fmaxf(mxv[ct], rowok ? Mv : -3e38f);
                const float cv = 1.0f - Mv * iir * icap[ct];     // C = 1 - cos
                av[ct] = (rowok && vw[ct]) ? __expf(-2.0f * cv) : 0.0f;
            }
            apk[j][0] = pkbf2(av[0], av[1]);
            apk[j][1] = pkbf2(av[2], av[3]);
        }
    }   // ---- acc out of scope ----

    // ---- t init (constants only; no acc dependency): t = T/sigma, t0 = m ----
    unsigned int tpk[12][2];
    {
        const unsigned int mm   = pkbf2(mf, mf);
        const unsigned int m0   = pkbf2(mf, 0.0f);
        const unsigned int zz   = 0u;
        unsigned int v01, v23;  // per-ct validity pattern for this lane
        v01 = vw[1] ? mm : (vw[0] ? m0 : zz);
        v23 = vw[3] ? mm : (vw[2] ? m0 : zz);
        #pragma unroll
        for (int j = 0; j < 12; ++j) {
            const bool rowok = (j < 8) || (q == 0);
            tpk[j][0] = rowok ? v01 : zz;
            tpk[j][1] = rowok ? v23 : zz;
        }
    }

    const int b = b0 + wv;
    // ---- MISA: mean_w max_r M ----
    {
        float sp = 0.0f;
        #pragma unroll
        for (int ct = 0; ct < 4; ++ct) {
            float v = mxv[ct];
            v = fmaxf(v, SWZ(v, 0x401F));
            v = fmaxf(v, BPERM(xaddr, v));
            sp += vw[ct] ? v : 0.0f;
        }
        sp = bfly64_sum(sp, xaddr);      // = 4 * sum_w colmax (q-replicated)
        if (lane == 0) S[(size_t)b * N_IMAGE + cap] = sp * inv_m * 0.25f;
    }

    // ---- IPOT: 20 iterations, all-VGPR, DPP row-sums ----
    float sig[4];
    #pragma unroll
    for (int ct = 0; ct < 4; ++ct) sig[ct] = vw[ct] ? inv_m : 0.0f;

    for (int it = 0; it < OT_ITERS; ++it) {
        float s2[4];
        #pragma unroll
        for (int ct = 0; ct < 4; ++ct) s2[ct] = sig[ct] * sig[ct];
        float csum[4] = {0.f, 0.f, 0.f, 0.f};
        #pragma unroll
        for (int j = 0; j < 12; ++j) {
            float at[4];
            at[0] = lo16(apk[j][0]) * lo16(tpk[j][0]);
            at[1] = hi16(apk[j][0]) * hi16(tpk[j][0]);
            at[2] = lo16(apk[j][1]) * lo16(tpk[j][1]);
            at[3] = hi16(apk[j][1]) * hi16(tpk[j][1]);
            float u = at[0] * s2[0];
            u = fmaf(at[1], s2[1], u);
            u = fmaf(at[2], s2[2], u);
            u = fmaf(at[3], s2[3], u);
            float R  = bfly16_sum(u);                        // row-sum: Σ_w Qσ
            float dl = __builtin_amdgcn_rcpf(36.0f * R);
            if (j >= 8) dl = (q == 0) ? dl : 0.0f;           // pad-row guard (R=0 -> inf)
            float tn[4];
            #pragma unroll
            for (int ct = 0; ct < 4; ++ct) {
                tn[ct] = at[ct] * (dl * sig[ct]);            // t_new = δQ
                csum[ct] += tn[ct];
            }
            tpk[j][0] = pkbf2(tn[0], tn[1]);
            tpk[j][1] = pkbf2(tn[2], tn[3]);
        }
        #pragma unroll
        for (int ct = 0; ct < 4; ++ct) {
            float cc = csum[ct];
            cc += SWZ(cc, 0x401F);                           // ^16 (across q)
            cc += BPERM(xaddr, cc);                          // ^32
            sig[ct] = vw[ct] ? __builtin_amdgcn_rcpf(mf * cc) : 0.0f;
        }
    }

    // ---- sims_ot = -Σ C∘T ;  C = -0.5 ln(A), T = t*sig ----
    {
        float pp = 0.0f;
        #pragma unroll
        for (int j = 0; j < 12; ++j) {
            float av[4], tv[4];
            av[0] = lo16(apk[j][0]); av[1] = hi16(apk[j][0]);
            av[2] = lo16(apk[j][1]); av[3] = hi16(apk[j][1]);
            tv[0] = lo16(tpk[j][0]); tv[1] = hi16(tpk[j][0]);
            tv[2] = lo16(tpk[j][1]); tv[3] = hi16(tpk[j][1]);
            #pragma unroll
            for (int ct = 0; ct < 4; ++ct) {
                const float cv = -0.5f * __logf(fmaxf(av[ct], 1e-30f));
                pp = fmaf(cv, tv[ct] * sig[ct], pp);
            }
        }
        pp = bfly64_sum(pp, xaddr);      // every cell counted once
        if (lane == 0) SOT[(size_t)b * N_IMAGE + cap] = -pp;
    }
}

// ---------------- loss: 128 blocks, one per row/col pair, atomic accumulate ----

__global__ void loss_kernel(const float* __restrict__ S, const float* __restrict__ SOT,
                            float* __restrict__ out) {
    const int j = blockIdx.x;
    const int t = threadIdx.x;           // 128 threads
    __shared__ float sh[4][2];
    const float db  = S[j * 129];        // diag
    const float dob = SOT[j * 129];
    float rv = 0.f, rov = 0.f, cv = 0.f, cov = 0.f;
    if (t != j) {
        float cs  = fmaxf(0.0f, MARGIN_F + S[j * 128 + t] - db);
        float cso = fmaxf(0.0f, MARGIN_F + SOT[j * 128 + t] - dob);
        rv = cs + ALPHA_F * cso;  rov = cso;
        float ci  = fmaxf(0.0f, MARGIN_F + S[t * 128 + j] - db);
        float cio = fmaxf(0.0f, MARGIN_F + SOT[t * 128 + j] - dob);
        cv = ci + ALPHA_F * cio;  cov = cio;
    }
    for (int off = 32; off; off >>= 1) {
        rv  = fmaxf(rv,  __shfl_down(rv,  off, 64));
        rov = fmaxf(rov, __shfl_down(rov, off, 64));
        cv  = fmaxf(cv,  __shfl_down(cv,  off, 64));
        cov = fmaxf(cov, __shfl_down(cov, off, 64));
    }
    if ((t & 63) == 0) {
        sh[0][t >> 6] = rv; sh[1][t >> 6] = rov;
        sh[2][t >> 6] = cv; sh[3][t >> 6] = cov;
    }
    __syncthreads();
    if (t == 0) {
        float a0 = fmaxf(sh[0][0], sh[0][1]) + fmaxf(sh[2][0], sh[2][1]);
        float a1 = fmaxf(sh[1][0], sh[1][1]) + fmaxf(sh[3][0], sh[3][1]);
        atomicAdd(&out[0], a0);
        atomicAdd(&out[1], a1);
    }
}

extern "C" void kernel_launch(void* const* d_in, const int* in_sizes, int n_in,
                              void* d_out, int out_size, void* d_ws, size_t ws_size,
                              hipStream_t stream) {
    const float* im  = (const float*)d_in[0];
    const float* s   = (const float*)d_in[1];
    const int*   s_l = (const int*)d_in[2];
    float* out = (float*)d_out;
    float* ws  = (float*)d_ws;

    float* inv_im  = ws;
    float* inv_cap = ws + 4608;
    float* S       = ws + 12288;
    float* SOT     = ws + 12288 + 16384;

    norms_kernel<<<dim3((4608 + 7680) / 4), dim3(256), 0, stream>>>(im, s, inv_im, inv_cap, out);
    pair_kernel<<<dim3(N_IMAGE, N_IMAGE / 4), dim3(256), 0, stream>>>(im, s, s_l, inv_im, inv_cap, S, SOT);
    loss_kernel<<<dim3(N_IMAGE), dim3(128), 0, stream>>>(S, SOT, out);
}

// Round 8
// 368.907 us; speedup vs baseline: 1.5508x; 1.5508x over previous
//
#include <hip/hip_runtime.h>
#include <hip/hip_bf16.h>
#include <math.h>

#define N_IMAGE 128
#define N_REG   36
#define DIM     1024
#define MAX_WORD 60
#define OT_ITERS 20
#define MARGIN_F 0.2f
#define ALPHA_F  0.1f
#define EPS_F    1e-12f

typedef short bf16x8 __attribute__((ext_vector_type(8)));
typedef float f32x4  __attribute__((ext_vector_type(4)));

// ---------------- helpers ----------------

__device__ __forceinline__ unsigned int pkbf2(float a, float b) {
    union { __hip_bfloat162 h2; unsigned int u; } cv;
    cv.h2 = __float22bfloat162_rn(make_float2(a, b));
    return cv.u;
}
__device__ __forceinline__ float lo16(unsigned int u) { return __int_as_float((int)(u << 16)); }
__device__ __forceinline__ float hi16(unsigned int u) { return __int_as_float((int)(u & 0xFFFF0000u)); }

#define SWZ(x, pat) __int_as_float(__builtin_amdgcn_ds_swizzle(__float_as_int(x), (pat)))
#define BPERM(a, x) __int_as_float(__builtin_amdgcn_ds_bpermute((a), __float_as_int(x)))
// DPP add: x += dpp_perm(x). VALU pipe, low latency (vs ~30cyc ds_swizzle).
#define DPPADD(x, ctrl) \
    ((x) + __int_as_float(__builtin_amdgcn_update_dpp(0, __float_as_int(x), (ctrl), 0xf, 0xf, true)))

// 16-lane group sum (all 16 lanes get the sum). Pure DPP/VALU.
__device__ __forceinline__ float bfly16_sum(float x) {
    x = DPPADD(x, 0xB1);    // quad_perm ^1
    x = DPPADD(x, 0x4E);    // quad_perm ^2
    x = DPPADD(x, 0x124);   // row_ror:4
    x = DPPADD(x, 0x128);   // row_ror:8
    return x;
}
// full 64-lane sum (all lanes)
__device__ __forceinline__ float bfly64_sum(float x, int xaddr) {
    x = bfly16_sum(x);
    x += SWZ(x, 0x401F);   // ^16
    x += BPERM(xaddr, x);  // ^32
    return x;
}

// ------- norms (+ optional bf16 conversion of inputs into ws, + zero d_out) -------

__global__ void norms_kernel(const float* __restrict__ im, const float* __restrict__ s,
                             float* __restrict__ inv_im, float* __restrict__ inv_cap,
                             float* __restrict__ out, int conv,
                             unsigned short* __restrict__ im16,
                             unsigned short* __restrict__ s16) {
    if (blockIdx.x == 0 && threadIdx.x == 0) { out[0] = 0.0f; out[1] = 0.0f; }
    const int NIM = N_IMAGE * N_REG;     // 4608
    const int NS  = N_IMAGE * MAX_WORD;  // 7680
    int row  = blockIdx.x * 4 + (threadIdx.x >> 6);
    int lane = threadIdx.x & 63;
    if (row >= NIM + NS) return;
    const bool isim = (row < NIM);
    const float* base = isim ? (im + (size_t)row * DIM)
                             : (s  + (size_t)(row - NIM) * DIM);
    unsigned short* dst = isim ? (im16 + (size_t)row * DIM)
                               : (s16  + (size_t)(row - NIM) * DIM);
    const float4* b4 = (const float4*)base;
    float acc = 0.0f;
    for (int k = lane; k < DIM / 4; k += 64) {
        float4 v = b4[k];
        acc += v.x * v.x + v.y * v.y + v.z * v.z + v.w * v.w;
        if (conv) {
            uint2 w2; w2.x = pkbf2(v.x, v.y); w2.y = pkbf2(v.z, v.w);
            *(uint2*)(dst + k * 4) = w2;
        }
    }
    for (int off = 32; off; off >>= 1) acc += __shfl_down(acc, off, 64);
    if (lane == 0) {
        float inv = 1.0f / (sqrtf(acc) + EPS_F);
        if (isim) inv_im[row] = inv;
        else      inv_cap[row - NIM] = inv;
    }
}

// ---------------- fused pair kernel ----------------
// Block = (caption i, image group of 4). Wave v owns pair (i, b0+v).
// GEMM: A and B both staged (coalesced) into LDS, 2 barriers/chunk (R5 scheme).
// D in MFMA C-layout: acc[rt*4+ct][p] = M[r][w], r = rt*16+q*4+p, w = ct*16+l15.
// OT: register-resident in C-layout; row-sums = 16-lane DPP butterflies (VALU),
// sigma-update = ^16 swizzle + ^32 bpermute.
// BF16IN: inputs pre-converted to bf16 (no per-chunk cvt, half the load bytes).

template <bool BF16IN>
__global__ __launch_bounds__(256, 4)
void pair_kernel(const float* __restrict__ im, const float* __restrict__ s,
                 const unsigned short* __restrict__ im16,
                 const unsigned short* __restrict__ s16,
                 const int* __restrict__ s_l,
                 const float* __restrict__ inv_im, const float* __restrict__ inv_cap,
                 float* __restrict__ S, float* __restrict__ SOT) {
    const int cap  = blockIdx.x;         // caption index i
    const int b0   = blockIdx.y * 4;     // first image of this block
    const int tid  = threadIdx.x;
    const int lane = tid & 63;
    const int wv   = tid >> 6;           // wave id = local image
    const int q    = lane >> 4;          // 16-lane group within wave
    const int l15  = lane & 15;
    const int q4   = tid & 15;           // staging column slot
    const int row0 = tid >> 4;           // staging row base (0..15)
    const int xaddr = ((lane ^ 32) << 2);

    // staging: 256 rows x 144B bf16 (192 A-rows padded to 48/img + 64 B-rows)
    __shared__ __align__(16) char smem[36864];
    __shared__ float invImS[144];
    __shared__ float invCapS[60];

    if (tid < 144) invImS[tid] = inv_im[b0 * 36 + tid];
    else if (tid < 204) invCapS[tid - 144] = inv_cap[cap * 60 + (tid - 144)];

    const int   m     = s_l[cap];        // n_word, 10..60
    const float mf    = (float)m;
    const float inv_m = 1.0f / mf;

    // zero staging once: pad rows (A r>=36, B r>=60) must be 0 for MFMA.
    {
        float4 z = make_float4(0.f, 0.f, 0.f, 0.f);
        #pragma unroll
        for (int j = 0; j < 9; ++j)
            *(float4*)(smem + (tid + j * 256) * 16) = z;
    }
    __syncthreads();

    const char* sA = smem;
    const char* sB = smem + 27648;

    f32x4 acc[12];
    #pragma unroll
    for (int t = 0; t < 12; ++t) acc[t] = (f32x4){0.f, 0.f, 0.f, 0.f};

    // ---- GEMM over K=1024 in 16 chunks of 64 ----
    for (int c = 0; c < 16; ++c) {
        const int col = c * 64 + q4 * 4;
        // A: 4 images x 3 row-slots
        #pragma unroll
        for (int img = 0; img < 4; ++img) {
            #pragma unroll
            for (int j = 0; j < 3; ++j) {
                const int r = row0 + 16 * j;                 // < 48
                if (j < 2 || row0 < 4) {                     // valid iff r < 36
                    const size_t ro = (size_t)(b0 * 36 + img * 36 + r) * 1024 + col;
                    uint2 w2;
                    if (BF16IN) {
                        w2 = *(const uint2*)(im16 + ro);
                    } else {
                        float4 v = *(const float4*)(im + ro);
                        w2.x = pkbf2(v.x, v.y); w2.y = pkbf2(v.z, v.w);
                    }
                    *(uint2*)(smem + (img * 48 + r) * 144 + q4 * 8) = w2;
                }
            }
        }
        // B: 4 row-slots
        #pragma unroll
        for (int j = 0; j < 4; ++j) {
            const int r = row0 + 16 * j;                     // < 64
            if (j < 3 || row0 < 12) {                        // valid iff r < 60
                const size_t ro = (size_t)(cap * 60 + r) * 1024 + col;
                uint2 w2;
                if (BF16IN) {
                    w2 = *(const uint2*)(s16 + ro);
                } else {
                    float4 v = *(const float4*)(s + ro);
                    w2.x = pkbf2(v.x, v.y); w2.y = pkbf2(v.z, v.w);
                }
                *(uint2*)(smem + (192 + r) * 144 + q4 * 8) = w2;
            }
        }
        __syncthreads();
        #pragma unroll
        for (int h = 0; h < 2; ++h) {
            bf16x8 bfr[4];
            #pragma unroll
            for (int ct = 0; ct < 4; ++ct)
                bfr[ct] = *(const bf16x8*)(sB + (ct * 16 + l15) * 144 + h * 64 + q * 16);
            #pragma unroll
            for (int rt = 0; rt < 3; ++rt) {
                bf16x8 afr = *(const bf16x8*)(sA + (wv * 48 + rt * 16 + l15) * 144 + h * 64 + q * 16);
                #pragma unroll
                for (int ct = 0; ct < 4; ++ct)
                    acc[rt * 4 + ct] = __builtin_amdgcn_mfma_f32_16x16x32_bf16(
                        afr, bfr[ct], acc[rt * 4 + ct], 0, 0, 0);
            }
        }
        __syncthreads();
    }

    // ---- OT setup in C-layout ----
    float icap[4]; bool vw[4];
    #pragma unroll
    for (int ct = 0; ct < 4; ++ct) {
        const int w = ct * 16 + l15;
        vw[ct]   = (w < m);
        icap[ct] = (w < 60) ? invCapS[w] : 0.0f;
    }

    float        t_[12][4];      // t = T/sigma
    unsigned int apk[12][2];     // A = exp(-2C), bf16-packed
    float mxv[4] = {-3e38f, -3e38f, -3e38f, -3e38f};

    #pragma unroll
    for (int j = 0; j < 12; ++j) {
        const int rt = j >> 2, p = j & 3;
        const int r  = rt * 16 + q * 4 + p;                  // < 48
        const bool rowok = (rt < 2) || (q == 0);             // r < 36
        const float iir = rowok ? invImS[wv * 36 + (r < 36 ? r : 0)] : 0.0f;
        float av[4];
        #pragma unroll
        for (int ct = 0; ct < 4; ++ct) {
            const float Mv = acc[rt * 4 + ct][p];
            mxv[ct] = fmaxf(mxv[ct], rowok ? Mv : -3e38f);
            const float cv = 1.0f - Mv * iir * icap[ct];     // C = 1 - cos
            const bool ok  = rowok && vw[ct];
            av[ct]    = ok ? __expf(-2.0f * cv) : 0.0f;      // A = exp(-C/beta)
            t_[j][ct] = ok ? mf : 0.0f;                      // t0 = T0/sig0 = m
        }
        apk[j][0] = pkbf2(av[0], av[1]);
        apk[j][1] = pkbf2(av[2], av[3]);
    }

    const int b = b0 + wv;
    // ---- MISA: mean_w max_r M ----
    {
        float sp = 0.0f;
        #pragma unroll
        for (int ct = 0; ct < 4; ++ct) {
            float v = mxv[ct];
            v = fmaxf(v, SWZ(v, 0x401F));
            v = fmaxf(v, BPERM(xaddr, v));
            sp += vw[ct] ? v : 0.0f;
        }
        sp = bfly64_sum(sp, xaddr);      // = 4 * sum_w colmax (q-replicated)
        if (lane == 0) S[(size_t)b * N_IMAGE + cap] = sp * inv_m * 0.25f;
    }

    // ---- IPOT: 20 iterations, register-resident, DPP row-sums ----
    float sig[4];
    #pragma unroll
    for (int ct = 0; ct < 4; ++ct) sig[ct] = vw[ct] ? inv_m : 0.0f;

    for (int it = 0; it < OT_ITERS; ++it) {
        float s2[4];
        #pragma unroll
        for (int ct = 0; ct < 4; ++ct) s2[ct] = sig[ct] * sig[ct];
        float csum[4] = {0.f, 0.f, 0.f, 0.f};
        #pragma unroll
        for (int j = 0; j < 12; ++j) {
            float at[4];
            at[0] = lo16(apk[j][0]) * t_[j][0];
            at[1] = hi16(apk[j][0]) * t_[j][1];
            at[2] = lo16(apk[j][1]) * t_[j][2];
            at[3] = hi16(apk[j][1]) * t_[j][3];
            float u = at[0] * s2[0];
            u = fmaf(at[1], s2[1], u);
            u = fmaf(at[2], s2[2], u);
            u = fmaf(at[3], s2[3], u);
            float R  = bfly16_sum(u);                        // row-sum: Σ_w Qσ
            float dl = __builtin_amdgcn_rcpf(36.0f * R);
            if (j >= 8) dl = (q == 0) ? dl : 0.0f;           // pad-row guard (R=0 -> inf)
            #pragma unroll
            for (int ct = 0; ct < 4; ++ct) {
                const float tn = at[ct] * (dl * sig[ct]);    // t_new = δQ
                t_[j][ct] = tn;
                csum[ct] += tn;
            }
        }
        #pragma unroll
        for (int ct = 0; ct < 4; ++ct) {
            float cc = csum[ct];
            cc += SWZ(cc, 0x401F);                           // ^16 (across q)
            cc += BPERM(xaddr, cc);                          // ^32
            sig[ct] = vw[ct] ? __builtin_amdgcn_rcpf(mf * cc) : 0.0f;
        }
    }

    // ---- sims_ot = -Σ C∘T ;  C = -0.5 ln(A), T = t*sig ----
    {
        float pp = 0.0f;
        #pragma unroll
        for (int j = 0; j < 12; ++j) {
            float av[4];
            av[0] = lo16(apk[j][0]); av[1] = hi16(apk[j][0]);
            av[2] = lo16(apk[j][1]); av[3] = hi16(apk[j][1]);
            #pragma unroll
            for (int ct = 0; ct < 4; ++ct) {
                const float cv = -0.5f * __logf(fmaxf(av[ct], 1e-30f));
                pp = fmaf(cv, t_[j][ct] * sig[ct], pp);
            }
        }
        pp = bfly64_sum(pp, xaddr);      // every cell counted once
        if (lane == 0) SOT[(size_t)b * N_IMAGE + cap] = -pp;
    }
}

// ---------------- loss: 128 blocks, one per row/col pair, atomic accumulate ----

__global__ void loss_kernel(const float* __restrict__ S, const float* __restrict__ SOT,
                            float* __restrict__ out) {
    const int j = blockIdx.x;
    const int t = threadIdx.x;           // 128 threads
    __shared__ float sh[4][2];
    const float db  = S[j * 129];        // diag
    const float dob = SOT[j * 129];
    float rv = 0.f, rov = 0.f, cv = 0.f, cov = 0.f;
    if (t != j) {
        float cs  = fmaxf(0.0f, MARGIN_F + S[j * 128 + t] - db);
        float cso = fmaxf(0.0f, MARGIN_F + SOT[j * 128 + t] - dob);
        rv = cs + ALPHA_F * cso;  rov = cso;
        float ci  = fmaxf(0.0f, MARGIN_F + S[t * 128 + j] - db);
        float cio = fmaxf(0.0f, MARGIN_F + SOT[t * 128 + j] - dob);
        cv = ci + ALPHA_F * cio;  cov = cio;
    }
    for (int off = 32; off; off >>= 1) {
        rv  = fmaxf(rv,  __shfl_down(rv,  off, 64));
        rov = fmaxf(rov, __shfl_down(rov, off, 64));
        cv  = fmaxf(cv,  __shfl_down(cv,  off, 64));
        cov = fmaxf(cov, __shfl_down(cov, off, 64));
    }
    if ((t & 63) == 0) {
        sh[0][t >> 6] = rv; sh[1][t >> 6] = rov;
        sh[2][t >> 6] = cv; sh[3][t >> 6] = cov;
    }
    __syncthreads();
    if (t == 0) {
        float a0 = fmaxf(sh[0][0], sh[0][1]) + fmaxf(sh[2][0], sh[2][1]);
        float a1 = fmaxf(sh[1][0], sh[1][1]) + fmaxf(sh[3][0], sh[3][1]);
        atomicAdd(&out[0], a0);
        atomicAdd(&out[1], a1);
    }
}

extern "C" void kernel_launch(void* const* d_in, const int* in_sizes, int n_in,
                              void* d_out, int out_size, void* d_ws, size_t ws_size,
                              hipStream_t stream) {
    const float* im  = (const float*)d_in[0];
    const float* s   = (const float*)d_in[1];
    const int*   s_l = (const int*)d_in[2];
    float* out = (float*)d_out;
    float* ws  = (float*)d_ws;

    float* inv_im  = ws;
    float* inv_cap = ws + 4608;
    float* S       = ws + 12288;
    float* SOT     = ws + 12288 + 16384;
    // bf16 conversion area after the 180224-byte float region
    unsigned short* im16 = (unsigned short*)((char*)d_ws + 180224);
    unsigned short* s16  = im16 + (size_t)N_IMAGE * N_REG * DIM;   // +4.7M shorts
    const size_t need = 180224 +
        ((size_t)N_IMAGE * N_REG * DIM + (size_t)N_IMAGE * MAX_WORD * DIM) * 2;
    const int fast = (ws_size >= need) ? 1 : 0;   // ws_size is call-invariant

    norms_kernel<<<dim3((4608 + 7680) / 4), dim3(256), 0, stream>>>(
        im, s, inv_im, inv_cap, out, fast, im16, s16);
    if (fast)
        pair_kernel<true><<<dim3(N_IMAGE, N_IMAGE / 4), dim3(256), 0, stream>>>(
            im, s, im16, s16, s_l, inv_im, inv_cap, S, SOT);
    else
        pair_kernel<false><<<dim3(N_IMAGE, N_IMAGE / 4), dim3(256), 0, stream>>>(
            im, s, im16, s16, s_l, inv_im, inv_cap, S, SOT);
    loss_kernel<<<dim3(N_IMAGE), dim3(128), 0, stream>>>(S, SOT, out);
}

// Round 9
// 338.377 us; speedup vs baseline: 1.6907x; 1.0902x over previous
//
#include <hip/hip_runtime.h>
#include <hip/hip_bf16.h>
#include <math.h>

#define N_IMAGE 128
#define N_REG   36
#define DIM     1024
#define MAX_WORD 60
#define OT_ITERS 20
#define MARGIN_F 0.2f
#define ALPHA_F  0.1f
#define EPS_F    1e-12f

typedef short bf16x8 __attribute__((ext_vector_type(8)));
typedef float f32x4  __attribute__((ext_vector_type(4)));

// ---------------- helpers ----------------

__device__ __forceinline__ unsigned int pkbf2(float a, float b) {
    union { __hip_bfloat162 h2; unsigned int u; } cv;
    cv.h2 = __float22bfloat162_rn(make_float2(a, b));
    return cv.u;
}
__device__ __forceinline__ float lo16(unsigned int u) { return __int_as_float((int)(u << 16)); }
__device__ __forceinline__ float hi16(unsigned int u) { return __int_as_float((int)(u & 0xFFFF0000u)); }

#define SWZ(x, pat) __int_as_float(__builtin_amdgcn_ds_swizzle(__float_as_int(x), (pat)))
#define BPERM(a, x) __int_as_float(__builtin_amdgcn_ds_bpermute((a), __float_as_int(x)))
// DPP add: x += dpp_perm(x). VALU pipe, low latency.
#define DPPADD(x, ctrl) \
    ((x) + __int_as_float(__builtin_amdgcn_update_dpp(0, __float_as_int(x), (ctrl), 0xf, 0xf, true)))

// 16-lane group sum (all 16 lanes get the sum). Pure DPP/VALU.
__device__ __forceinline__ float bfly16_sum(float x) {
    x = DPPADD(x, 0xB1);    // quad_perm ^1
    x = DPPADD(x, 0x4E);    // quad_perm ^2
    x = DPPADD(x, 0x124);   // row_ror:4
    x = DPPADD(x, 0x128);   // row_ror:8
    return x;
}
// full 64-lane sum (all lanes)
__device__ __forceinline__ float bfly64_sum(float x, int xaddr) {
    x = bfly16_sum(x);
    x += SWZ(x, 0x401F);   // ^16
    x += BPERM(xaddr, x);  // ^32
    return x;
}

// ------- norms (+ optional bf16 conversion of inputs into ws, + zero d_out) -------

__global__ void norms_kernel(const float* __restrict__ im, const float* __restrict__ s,
                             float* __restrict__ inv_im, float* __restrict__ inv_cap,
                             float* __restrict__ out, int conv,
                             unsigned short* __restrict__ im16,
                             unsigned short* __restrict__ s16) {
    if (blockIdx.x == 0 && threadIdx.x == 0) { out[0] = 0.0f; out[1] = 0.0f; }
    const int NIM = N_IMAGE * N_REG;     // 4608
    const int NS  = N_IMAGE * MAX_WORD;  // 7680
    int row  = blockIdx.x * 4 + (threadIdx.x >> 6);
    int lane = threadIdx.x & 63;
    if (row >= NIM + NS) return;
    const bool isim = (row < NIM);
    const float* base = isim ? (im + (size_t)row * DIM)
                             : (s  + (size_t)(row - NIM) * DIM);
    unsigned short* dst = isim ? (im16 + (size_t)row * DIM)
                               : (s16  + (size_t)(row - NIM) * DIM);
    const float4* b4 = (const float4*)base;
    float acc = 0.0f;
    for (int k = lane; k < DIM / 4; k += 64) {
        float4 v = b4[k];
        acc += v.x * v.x + v.y * v.y + v.z * v.z + v.w * v.w;
        if (conv) {
            uint2 w2; w2.x = pkbf2(v.x, v.y); w2.y = pkbf2(v.z, v.w);
            *(uint2*)(dst + k * 4) = w2;
        }
    }
    for (int off = 32; off; off >>= 1) acc += __shfl_down(acc, off, 64);
    if (lane == 0) {
        float inv = 1.0f / (sqrtf(acc) + EPS_F);
        if (isim) inv_im[row] = inv;
        else      inv_cap[row - NIM] = inv;
    }
}

// ---------------- pair body, specialized on CT = ceil(m/16) in 1..4 ----------------
// Block = (caption i, image group of 4). Wave v owns pair (i, b0+v).
// Only the first CT 16-column groups are staged / MFMA'd / iterated in OT:
// columns w >= CT*16 would be exact zeros everywhere, so skipping them is exact.

template <bool BF16IN, int CT>
__device__ __forceinline__ void pair_body(
    const float* __restrict__ im, const float* __restrict__ s,
    const unsigned short* __restrict__ im16, const unsigned short* __restrict__ s16,
    char* smem, const float* invImS, const float* invCapS,
    int cap, int b0, int m,
    float* __restrict__ S, float* __restrict__ SOT) {

    const int tid  = threadIdx.x;
    const int lane = tid & 63;
    const int wv   = tid >> 6;
    const int q    = lane >> 4;
    const int l15  = lane & 15;
    const int q4   = tid & 15;
    const int row0 = tid >> 4;
    const int xaddr = ((lane ^ 32) << 2);

    const float mf    = (float)m;
    const float inv_m = 1.0f / mf;

    const char* sA = smem;
    const char* sB = smem + 27648;

    f32x4 acc[3 * CT];
    #pragma unroll
    for (int t = 0; t < 3 * CT; ++t) acc[t] = (f32x4){0.f, 0.f, 0.f, 0.f};

    // ---- GEMM over K=1024 in 16 chunks of 64 ----
    for (int c = 0; c < 16; ++c) {
        const int col = c * 64 + q4 * 4;
        // A: 4 images x 3 row-slots
        #pragma unroll
        for (int img = 0; img < 4; ++img) {
            #pragma unroll
            for (int j = 0; j < 3; ++j) {
                const int r = row0 + 16 * j;                 // < 48
                if (j < 2 || row0 < 4) {                     // valid iff r < 36
                    const size_t ro = (size_t)(b0 * 36 + img * 36 + r) * 1024 + col;
                    uint2 w2;
                    if (BF16IN) {
                        w2 = *(const uint2*)(im16 + ro);
                    } else {
                        float4 v = *(const float4*)(im + ro);
                        w2.x = pkbf2(v.x, v.y); w2.y = pkbf2(v.z, v.w);
                    }
                    *(uint2*)(smem + (img * 48 + r) * 144 + q4 * 8) = w2;
                }
            }
        }
        // B: only CT row-slots (rows < CT*16; for CT=4 clip to 60)
        #pragma unroll
        for (int j = 0; j < CT; ++j) {
            const int r = row0 + 16 * j;
            if (CT < 4 || j < 3 || row0 < 12) {              // r < min(CT*16, 60)
                const size_t ro = (size_t)(cap * 60 + r) * 1024 + col;
                uint2 w2;
                if (BF16IN) {
                    w2 = *(const uint2*)(s16 + ro);
                } else {
                    float4 v = *(const float4*)(s + ro);
                    w2.x = pkbf2(v.x, v.y); w2.y = pkbf2(v.z, v.w);
                }
                *(uint2*)(smem + (192 + r) * 144 + q4 * 8) = w2;
            }
        }
        __syncthreads();
        #pragma unroll
        for (int h = 0; h < 2; ++h) {
            bf16x8 bfr[CT];
            #pragma unroll
            for (int ct = 0; ct < CT; ++ct)
                bfr[ct] = *(const bf16x8*)(sB + (ct * 16 + l15) * 144 + h * 64 + q * 16);
            #pragma unroll
            for (int rt = 0; rt < 3; ++rt) {
                bf16x8 afr = *(const bf16x8*)(sA + (wv * 48 + rt * 16 + l15) * 144 + h * 64 + q * 16);
                #pragma unroll
                for (int ct = 0; ct < CT; ++ct)
                    acc[rt * CT + ct] = __builtin_amdgcn_mfma_f32_16x16x32_bf16(
                        afr, bfr[ct], acc[rt * CT + ct], 0, 0, 0);
            }
        }
        __syncthreads();
    }

    // ---- OT setup in C-layout ----
    constexpr int PK = (CT + 1) / 2;
    float icap[CT]; bool vw[CT];
    #pragma unroll
    for (int ct = 0; ct < CT; ++ct) {
        const int w = ct * 16 + l15;
        vw[ct]   = (w < m);
        icap[ct] = (w < 60) ? invCapS[w] : 0.0f;
    }

    float        t_[12][CT];     // t = T/sigma
    unsigned int apk[12][PK];    // A = exp(-2C), bf16-packed
    float mxv[CT];
    #pragma unroll
    for (int ct = 0; ct < CT; ++ct) mxv[ct] = -3e38f;

    #pragma unroll
    for (int j = 0; j < 12; ++j) {
        const int rt = j >> 2, p = j & 3;
        const int r  = rt * 16 + q * 4 + p;                  // < 48
        const bool rowok = (rt < 2) || (q == 0);             // r < 36
        const float iir = rowok ? invImS[wv * 36 + (r < 36 ? r : 0)] : 0.0f;
        float av[CT];
        #pragma unroll
        for (int ct = 0; ct < CT; ++ct) {
            const float Mv = acc[rt * CT + ct][p];
            mxv[ct] = fmaxf(mxv[ct], rowok ? Mv : -3e38f);
            const float cv = 1.0f - Mv * iir * icap[ct];     // C = 1 - cos
            const bool ok  = rowok && vw[ct];
            av[ct]    = ok ? __expf(-2.0f * cv) : 0.0f;      // A = exp(-C/beta)
            t_[j][ct] = ok ? mf : 0.0f;                      // t0 = T0/sig0 = m
        }
        #pragma unroll
        for (int pk = 0; pk < PK; ++pk)
            apk[j][pk] = pkbf2(av[2 * pk], (2 * pk + 1 < CT) ? av[2 * pk + 1] : 0.0f);
    }

    const int b = b0 + wv;
    // ---- MISA: mean_w max_r M ----
    {
        float sp = 0.0f;
        #pragma unroll
        for (int ct = 0; ct < CT; ++ct) {
            float v = mxv[ct];
            v = fmaxf(v, SWZ(v, 0x401F));
            v = fmaxf(v, BPERM(xaddr, v));
            sp += vw[ct] ? v : 0.0f;
        }
        sp = bfly64_sum(sp, xaddr);      // = 4 * sum_w colmax (q-replicated)
        if (lane == 0) S[(size_t)b * N_IMAGE + cap] = sp * inv_m * 0.25f;
    }

    // ---- IPOT: 20 iterations, register-resident, DPP row-sums ----
    float sig[CT];
    #pragma unroll
    for (int ct = 0; ct < CT; ++ct) sig[ct] = vw[ct] ? inv_m : 0.0f;

    for (int it = 0; it < OT_ITERS; ++it) {
        float s2[CT];
        #pragma unroll
        for (int ct = 0; ct < CT; ++ct) s2[ct] = sig[ct] * sig[ct];
        float csum[CT];
        #pragma unroll
        for (int ct = 0; ct < CT; ++ct) csum[ct] = 0.0f;
        #pragma unroll
        for (int j = 0; j < 12; ++j) {
            float at[CT];
            #pragma unroll
            for (int ct = 0; ct < CT; ++ct) {
                const float a = (ct & 1) ? hi16(apk[j][ct >> 1]) : lo16(apk[j][ct >> 1]);
                at[ct] = a * t_[j][ct];
            }
            float u = at[0] * s2[0];
            #pragma unroll
            for (int ct = 1; ct < CT; ++ct) u = fmaf(at[ct], s2[ct], u);
            float R  = bfly16_sum(u);                        // row-sum: Σ_w Qσ
            float dl = __builtin_amdgcn_rcpf(36.0f * R);
            if (j >= 8) dl = (q == 0) ? dl : 0.0f;           // pad-row guard (R=0 -> inf)
            #pragma unroll
            for (int ct = 0; ct < CT; ++ct) {
                const float tn = at[ct] * (dl * sig[ct]);    // t_new = δQ
                t_[j][ct] = tn;
                csum[ct] += tn;
            }
        }
        #pragma unroll
        for (int ct = 0; ct < CT; ++ct) {
            float cc = csum[ct];
            cc += SWZ(cc, 0x401F);                           // ^16 (across q)
            cc += BPERM(xaddr, cc);                          // ^32
            sig[ct] = vw[ct] ? __builtin_amdgcn_rcpf(mf * cc) : 0.0f;
        }
    }

    // ---- sims_ot = -Σ C∘T ;  C = -0.5 ln(A), T = t*sig ----
    {
        float pp = 0.0f;
        #pragma unroll
        for (int j = 0; j < 12; ++j) {
            #pragma unroll
            for (int ct = 0; ct < CT; ++ct) {
                const float a  = (ct & 1) ? hi16(apk[j][ct >> 1]) : lo16(apk[j][ct >> 1]);
                const float cv = -0.5f * __logf(fmaxf(a, 1e-30f));
                pp = fmaf(cv, t_[j][ct] * sig[ct], pp);
            }
        }
        pp = bfly64_sum(pp, xaddr);      // every cell counted once
        if (lane == 0) SOT[(size_t)b * N_IMAGE + cap] = -pp;
    }
}

template <bool BF16IN>
__global__ __launch_bounds__(256, 4)
void pair_kernel(const float* __restrict__ im, const float* __restrict__ s,
                 const unsigned short* __restrict__ im16,
                 const unsigned short* __restrict__ s16,
                 const int* __restrict__ s_l,
                 const float* __restrict__ inv_im, const float* __restrict__ inv_cap,
                 float* __restrict__ S, float* __restrict__ SOT) {
    const int cap = blockIdx.x;
    const int b0  = blockIdx.y * 4;
    const int tid = threadIdx.x;

    __shared__ __align__(16) char smem[36864];
    __shared__ float invImS[144];
    __shared__ float invCapS[60];

    if (tid < 144) invImS[tid] = inv_im[b0 * 36 + tid];
    else if (tid < 204) invCapS[tid - 144] = inv_cap[cap * 60 + (tid - 144)];

    const int m = s_l[cap];              // n_word, 10..60 (uniform per block)

    // zero staging once: pad rows (A r>=36, B r>=60/CT*16) must be 0 for MFMA.
    {
        float4 z = make_float4(0.f, 0.f, 0.f, 0.f);
        #pragma unroll
        for (int j = 0; j < 9; ++j)
            *(float4*)(smem + (tid + j * 256) * 16) = z;
    }
    __syncthreads();

    const int CT = __builtin_amdgcn_readfirstlane((m + 15) >> 4);   // 1..4
    switch (CT) {
    case 1: pair_body<BF16IN, 1>(im, s, im16, s16, smem, invImS, invCapS, cap, b0, m, S, SOT); break;
    case 2: pair_body<BF16IN, 2>(im, s, im16, s16, smem, invImS, invCapS, cap, b0, m, S, SOT); break;
    case 3: pair_body<BF16IN, 3>(im, s, im16, s16, smem, invImS, invCapS, cap, b0, m, S, SOT); break;
    default: pair_body<BF16IN, 4>(im, s, im16, s16, smem, invImS, invCapS, cap, b0, m, S, SOT); break;
    }
}

// ---------------- loss: 128 blocks, one per row/col pair, atomic accumulate ----

__global__ void loss_kernel(const float* __restrict__ S, const float* __restrict__ SOT,
                            float* __restrict__ out) {
    const int j = blockIdx.x;
    const int t = threadIdx.x;           // 128 threads
    __shared__ float sh[4][2];
    const float db  = S[j * 129];        // diag
    const float dob = SOT[j * 129];
    float rv = 0.f, rov = 0.f, cv = 0.f, cov = 0.f;
    if (t != j) {
        float cs  = fmaxf(0.0f, MARGIN_F + S[j * 128 + t] - db);
        float cso = fmaxf(0.0f, MARGIN_F + SOT[j * 128 + t] - dob);
        rv = cs + ALPHA_F * cso;  rov = cso;
        float ci  = fmaxf(0.0f, MARGIN_F + S[t * 128 + j] - db);
        float cio = fmaxf(0.0f, MARGIN_F + SOT[t * 128 + j] - dob);
        cv = ci + ALPHA_F * cio;  cov = cio;
    }
    for (int off = 32; off; off >>= 1) {
        rv  = fmaxf(rv,  __shfl_down(rv,  off, 64));
        rov = fmaxf(rov, __shfl_down(rov, off, 64));
        cv  = fmaxf(cv,  __shfl_down(cv,  off, 64));
        cov = fmaxf(cov, __shfl_down(cov, off, 64));
    }
    if ((t & 63) == 0) {
        sh[0][t >> 6] = rv; sh[1][t >> 6] = rov;
        sh[2][t >> 6] = cv; sh[3][t >> 6] = cov;
    }
    __syncthreads();
    if (t == 0) {
        float a0 = fmaxf(sh[0][0], sh[0][1]) + fmaxf(sh[2][0], sh[2][1]);
        float a1 = fmaxf(sh[1][0], sh[1][1]) + fmaxf(sh[3][0], sh[3][1]);
        atomicAdd(&out[0], a0);
        atomicAdd(&out[1], a1);
    }
}

extern "C" void kernel_launch(void* const* d_in, const int* in_sizes, int n_in,
                              void* d_out, int out_size, void* d_ws, size_t ws_size,
                              hipStream_t stream) {
    const float* im  = (const float*)d_in[0];
    const float* s   = (const float*)d_in[1];
    const int*   s_l = (const int*)d_in[2];
    float* out = (float*)d_out;
    float* ws  = (float*)d_ws;

    float* inv_im  = ws;
    float* inv_cap = ws + 4608;
    float* S       = ws + 12288;
    float* SOT     = ws + 12288 + 16384;
    // bf16 conversion area after the 180224-byte float region
    unsigned short* im16 = (unsigned short*)((char*)d_ws + 180224);
    unsigned short* s16  = im16 + (size_t)N_IMAGE * N_REG * DIM;
    const size_t need = 180224 +
        ((size_t)N_IMAGE * N_REG * DIM + (size_t)N_IMAGE * MAX_WORD * DIM) * 2;
    const int fast = (ws_size >= need) ? 1 : 0;   // ws_size is call-invariant

    norms_kernel<<<dim3((4608 + 7680) / 4), dim3(256), 0, stream>>>(
        im, s, inv_im, inv_cap, out, fast, im16, s16);
    if (fast)
        pair_kernel<true><<<dim3(N_IMAGE, N_IMAGE / 4), dim3(256), 0, stream>>>(
            im, s, im16, s16, s_l, inv_im, inv_cap, S, SOT);
    else
        pair_kernel<false><<<dim3(N_IMAGE, N_IMAGE / 4), dim3(256), 0, stream>>>(
            im, s, im16, s16, s_l, inv_im, inv_cap, S, SOT);
    loss_kernel<<<dim3(N_IMAGE), dim3(128), 0, stream>>>(S, SOT, out);
}